// Round 4
// baseline (277.862 us; speedup 1.0000x reference)
//
#include <hip/hip_runtime.h>
#include <hip/hip_fp16.h>
#include <math.h>

#define V_   6890
#define FC_  13776
#define N_   2
#define H_   336
#define W_   336
#define K_   28
#define NPIX (N_*H_*W_)

#define SIGMA_INV 1.0e4f
#define GAMMA_INV 1.0e4f
#define EPS_      1e-10f
#define ZFAR_     100.0f
#define ZSCALE    (1.0f/99.0f)
#define LOG2E     1.442695041f

static __device__ __forceinline__ float fexp(float x)  { return __builtin_amdgcn_exp2f(x * LOG2E); }
static __device__ __forceinline__ float frcp(float x)  { return __builtin_amdgcn_rcpf(x); }
static __device__ __forceinline__ float frsq(float x)  { return __builtin_amdgcn_rsqf(x); }

// ws layout: [0, 3*V floats) vertex-normal accumulator (fp32, atomics);
// then fp16 face table, 32 halfs (64 B) per face:
//   halfs 0..8  : p0,p1,p2   halfs 9..17 : c0,c1,c2   halfs 18..26: n0,n1,n2
#define FD_OFFSET 82944   // align_up(3*6890*4, 256)

__global__ __launch_bounds__(256)
void face_pass1(const float* __restrict__ verts,
                const float* __restrict__ vcol,
                const int*   __restrict__ faces,
                float* __restrict__ vnAcc,
                __half2* __restrict__ fd) {
    int i = blockIdx.x * blockDim.x + threadIdx.x;
    if (i >= FC_) return;
    int f0 = faces[i*3+0], f1 = faces[i*3+1], f2 = faces[i*3+2];
    float a[18];
    a[0] = verts[f0*3+0]; a[1] = verts[f0*3+1]; a[2] = verts[f0*3+2];
    a[3] = verts[f1*3+0]; a[4] = verts[f1*3+1]; a[5] = verts[f1*3+2];
    a[6] = verts[f2*3+0]; a[7] = verts[f2*3+1]; a[8] = verts[f2*3+2];
    float e1x = a[3]-a[0], e1y = a[4]-a[1], e1z = a[5]-a[2];
    float e2x = a[6]-a[0], e2y = a[7]-a[1], e2z = a[8]-a[2];
    float fnx = e1y*e2z - e1z*e2y;
    float fny = e1z*e2x - e1x*e2z;
    float fnz = e1x*e2y - e1y*e2x;
    atomicAdd(&vnAcc[f0*3+0], fnx); atomicAdd(&vnAcc[f0*3+1], fny); atomicAdd(&vnAcc[f0*3+2], fnz);
    atomicAdd(&vnAcc[f1*3+0], fnx); atomicAdd(&vnAcc[f1*3+1], fny); atomicAdd(&vnAcc[f1*3+2], fnz);
    atomicAdd(&vnAcc[f2*3+0], fnx); atomicAdd(&vnAcc[f2*3+1], fny); atomicAdd(&vnAcc[f2*3+2], fnz);
    a[9]  = vcol[f0*3+0]; a[10] = vcol[f0*3+1]; a[11] = vcol[f0*3+2];
    a[12] = vcol[f1*3+0]; a[13] = vcol[f1*3+1]; a[14] = vcol[f1*3+2];
    a[15] = vcol[f2*3+0]; a[16] = vcol[f2*3+1]; a[17] = vcol[f2*3+2];
    __half2* o = fd + (size_t)i * 16;
    #pragma unroll
    for (int t = 0; t < 9; ++t) o[t] = __floats2half2_rn(a[2*t], a[2*t+1]);
}

__global__ __launch_bounds__(256)
void face_pass2(const int* __restrict__ faces,
                const float* __restrict__ vn,
                __half2* __restrict__ fd) {
    int i = blockIdx.x * blockDim.x + threadIdx.x;
    if (i >= FC_) return;
    int fidx[3] = { faces[i*3+0], faces[i*3+1], faces[i*3+2] };
    float b[10];
    #pragma unroll
    for (int v = 0; v < 3; ++v) {
        float x = vn[fidx[v]*3+0], y = vn[fidx[v]*3+1], z = vn[fidx[v]*3+2];
        float inv = frsq(fmaxf(x*x + y*y + z*z, 1e-12f));
        b[v*3+0] = x*inv; b[v*3+1] = y*inv; b[v*3+2] = z*inv;
    }
    b[9] = 0.0f;
    __half2* o = fd + (size_t)i * 16 + 9;
    #pragma unroll
    for (int t = 0; t < 5; ++t) o[t] = __floats2half2_rn(b[2*t], b[2*t+1]);
}

static __device__ __forceinline__ void shade_one(
    const __half* __restrict__ h, float w0, float w1, float w2,
    float lx, float ly, float lz,
    float ax, float ay, float az,
    float dcx, float dcy, float dcz,
    float scx, float scy, float scz,
    float camx, float camy, float camz,
    float& cr, float& cg, float& cb) {
    float px = w0*__half2float(h[0]) + w1*__half2float(h[3]) + w2*__half2float(h[6]);
    float py = w0*__half2float(h[1]) + w1*__half2float(h[4]) + w2*__half2float(h[7]);
    float pz = w0*__half2float(h[2]) + w1*__half2float(h[5]) + w2*__half2float(h[8]);
    float tr = w0*__half2float(h[9])  + w1*__half2float(h[12]) + w2*__half2float(h[15]);
    float tg = w0*__half2float(h[10]) + w1*__half2float(h[13]) + w2*__half2float(h[16]);
    float tb = w0*__half2float(h[11]) + w1*__half2float(h[14]) + w2*__half2float(h[17]);
    float nux = w0*__half2float(h[18]) + w1*__half2float(h[21]) + w2*__half2float(h[24]);
    float nuy = w0*__half2float(h[19]) + w1*__half2float(h[22]) + w2*__half2float(h[25]);
    float nuz = w0*__half2float(h[20]) + w1*__half2float(h[23]) + w2*__half2float(h[26]);
    float ninv = frsq(fmaxf(nux*nux + nuy*nuy + nuz*nuz, 1e-12f));
    float nx = nux*ninv, ny = nuy*ninv, nz = nuz*ninv;

    float lvx = lx - px, lvy = ly - py, lvz = lz - pz;
    float linv = frsq(fmaxf(lvx*lvx + lvy*lvy + lvz*lvz, 1e-12f));
    lvx *= linv; lvy *= linv; lvz *= linv;
    float ldn = lvx*nx + lvy*ny + lvz*nz;
    float ndotl = fmaxf(ldn, 0.0f);

    float vvx = camx - px, vvy = camy - py, vvz = camz - pz;
    float vinv = frsq(fmaxf(vvx*vvx + vvy*vvy + vvz*vvz, 1e-12f));
    vvx *= vinv; vvy *= vinv; vvz *= vinv;

    float rx = 2.0f*ldn*nx - lvx;
    float ry = 2.0f*ldn*ny - lvy;
    float rz = 2.0f*ldn*nz - lvz;
    float ca = fmaxf(rx*vvx + ry*vvy + rz*vvz, 0.0f);
    float p64 = ca*ca; p64 *= p64; p64 *= p64; p64 *= p64; p64 *= p64; p64 *= p64;

    cr = (ax + dcx*ndotl)*tr + scx*p64;
    cg = (ay + dcy*ndotl)*tg + scy*p64;
    cb = (az + dcz*ndotl)*tb + scz*p64;
}

// 16 lanes per pixel; lane j (0..13) handles samples k=2j, 2j+1.
__global__ __launch_bounds__(256)
void pixel_kernel(const int*   __restrict__ ptf,
                  const float* __restrict__ bary,
                  const float* __restrict__ dists,
                  const float* __restrict__ zbuf,
                  const ushort* __restrict__ fd16,
                  const float* __restrict__ light,
                  const float* __restrict__ amb,
                  const float* __restrict__ dif,
                  const float* __restrict__ spec,
                  const float* __restrict__ cam,
                  float* __restrict__ out) {
    int tid = blockIdx.x * blockDim.x + threadIdx.x;
    int pix = tid >> 4;
    int j   = tid & 15;
    if (pix >= NPIX) return;

    // uniform constants (scalar loads)
    float lx = light[0], ly = light[1], lz = light[2];
    float ax = amb[0],   ay = amb[1],   az = amb[2];
    float dcx = dif[0],  dcy = dif[1],  dcz = dif[2];
    float scx = spec[0], scy = spec[1], scz = spec[2];
    float camx = cam[0], camy = cam[1], camz = cam[2];

    bool act = (j < 14);
    size_t sbase = (size_t)pix * K_ + 2*j;

    int pf0 = -1, pf1 = -1;
    float d0 = 0.f, d1 = 0.f, z0 = ZFAR_, z1 = ZFAR_;
    float b00 = 0.f, b01 = 0.f, b02 = 0.f, b10 = 0.f, b11 = 0.f, b12 = 0.f;
    if (act) {
        int2   p2 = *(const int2*)  (ptf   + sbase);
        float2 dd = *(const float2*)(dists + sbase);
        float2 zz = *(const float2*)(zbuf  + sbase);
        const float2* bb = (const float2*)(bary + sbase*3);
        float2 ba = bb[0], bbv = bb[1], bc = bb[2];
        *(float2*)(out + (size_t)NPIX*4 + sbase) = zz;   // zbuf passthrough
        pf0 = p2.x; pf1 = p2.y;
        d0 = dd.x; d1 = dd.y; z0 = zz.x; z1 = zz.y;
        b00 = ba.x; b01 = ba.y; b02 = bbv.x;
        b10 = bbv.y; b11 = bc.x; b12 = bc.y;
    }

    // branchless gathers (clamped index; weight forced to 0 for masked)
    int i0 = pf0 >= 0 ? pf0 : 0;
    int i1 = pf1 >= 0 ? pf1 : 0;
    union Blob { uint4 u[4]; __half h[32]; };
    Blob F0, F1;
    {
        const uint4* q0 = (const uint4*)(fd16 + (size_t)i0 * 32);
        const uint4* q1 = (const uint4*)(fd16 + (size_t)i1 * 32);
        F0.u[0] = q0[0]; F0.u[1] = q0[1]; F0.u[2] = q0[2]; F0.u[3] = q0[3];
        F1.u[0] = q1[0]; F1.u[1] = q1[1]; F1.u[2] = q1[2]; F1.u[3] = q1[3];
    }

    float cr0, cg0, cb0, cr1, cg1, cb1;
    shade_one(F0.h, b00, b01, b02, lx,ly,lz, ax,ay,az, dcx,dcy,dcz, scx,scy,scz, camx,camy,camz, cr0,cg0,cb0);
    shade_one(F1.h, b10, b11, b12, lx,ly,lz, ax,ay,az, dcx,dcy,dcz, scx,scy,scz, camx,camy,camz, cr1,cg1,cb1);

    float prob0 = pf0 >= 0 ? frcp(1.0f + fexp(d0 * SIGMA_INV)) : 0.0f;
    float prob1 = pf1 >= 0 ? frcp(1.0f + fexp(d1 * SIGMA_INV)) : 0.0f;
    float zi0 = pf0 >= 0 ? (ZFAR_ - z0) * ZSCALE : 0.0f;   // z in [2,12] -> zi in [0.89,0.99]
    float zi1 = pf1 >= 0 ? (ZFAR_ - z1) * ZSCALE : 0.0f;

    // zbuf sorted ascending -> z_inv descending -> max over active = first active sample.
    float cand = pf0 >= 0 ? zi0 : zi1;
    bool  has  = (pf0 >= 0) || (pf1 >= 0);
    unsigned long long mk = __ballot(has);
    int wavelane  = threadIdx.x & 63;
    int groupbase = wavelane & ~15;
    unsigned gm = (unsigned)((mk >> groupbase) & 0xFFFFull);
    float m = EPS_;
    int src = groupbase + (gm ? (int)__builtin_ctz(gm) : 0);
    float mshfl = __shfl(cand, src, 64);
    if (gm) m = mshfl;

    float w0s = prob0 * fexp((zi0 - m) * GAMMA_INV);
    float w1s = prob1 * fexp((zi1 - m) * GAMMA_INV);
    float w   = w0s + w1s;
    float swr = w0s*cr0 + w1s*cr1;
    float swg = w0s*cg0 + w1s*cg1;
    float swb = w0s*cb0 + w1s*cb1;
    float om  = (1.0f - prob0) * (1.0f - prob1);

    #pragma unroll
    for (int o = 8; o; o >>= 1) {
        w   += __shfl_xor(w,   o, 16);
        swr += __shfl_xor(swr, o, 16);
        swg += __shfl_xor(swg, o, 16);
        swb += __shfl_xor(swb, o, 16);
        om  *= __shfl_xor(om,  o, 16);
    }

    if (j == 0) {
        float deltaw = fexp((EPS_ - m) * GAMMA_INV);
        float inv = frcp(w + deltaw);
        float4 img;
        img.x = (swr + deltaw) * inv;   // BG = 1
        img.y = (swg + deltaw) * inv;
        img.z = (swb + deltaw) * inv;
        img.w = 1.0f - om;
        ((float4*)out)[pix] = img;
    }
}

extern "C" void kernel_launch(void* const* d_in, const int* in_sizes, int n_in,
                              void* d_out, int out_size, void* d_ws, size_t ws_size,
                              hipStream_t stream) {
    const float* verts = (const float*)d_in[0];
    const float* vcol  = (const float*)d_in[1];
    const int*   faces = (const int*)d_in[2];
    const int*   ptf   = (const int*)d_in[3];
    const float* bary  = (const float*)d_in[4];
    const float* dists = (const float*)d_in[5];
    const float* zbuf  = (const float*)d_in[6];
    const float* light = (const float*)d_in[7];
    const float* amb   = (const float*)d_in[8];
    const float* dif   = (const float*)d_in[9];
    const float* spec  = (const float*)d_in[10];
    const float* cam   = (const float*)d_in[11];
    float* out = (float*)d_out;

    float*   vnAcc = (float*)d_ws;
    __half2* fdat  = (__half2*)((char*)d_ws + FD_OFFSET);

    hipMemsetAsync(vnAcc, 0, (size_t)V_ * 3 * sizeof(float), stream);
    face_pass1<<<(FC_ + 255)/256, 256, 0, stream>>>(verts, vcol, faces, vnAcc, fdat);
    face_pass2<<<(FC_ + 255)/256, 256, 0, stream>>>(faces, vnAcc, fdat);

    int blocks = (NPIX * 16 + 255) / 256;
    pixel_kernel<<<blocks, 256, 0, stream>>>(
        ptf, bary, dists, zbuf, (const ushort*)fdat,
        light, amb, dif, spec, cam, out);
}

// Round 5
// 243.862 us; speedup vs baseline: 1.1394x; 1.1394x over previous
//
#include <hip/hip_runtime.h>
#include <hip/hip_fp16.h>
#include <math.h>

#define V_   6890
#define FC_  13776
#define N_   2
#define H_   336
#define W_   336
#define K_   28
#define NPIX (N_*H_*W_)

#define SIGMA_INV 1.0e4f
#define GAMMA_INV 1.0e4f
#define EPS_      1e-10f
#define ZFAR_     100.0f
#define ZSCALE    (1.0f/99.0f)
#define LOG2E     1.442695041f

static __device__ __forceinline__ float fexp(float x)  { return __builtin_amdgcn_exp2f(x * LOG2E); }
static __device__ __forceinline__ float frcp(float x)  { return __builtin_amdgcn_rcpf(x); }
static __device__ __forceinline__ float frsq(float x)  { return __builtin_amdgcn_rsqf(x); }

// ws layout: [0, 3*V floats) vertex-normal accumulator (fp32, atomics);
// then packed face table, 48 B per face (3 x uint4):
//   halfs h[0..8]  : p0,p1,p2   (fp16)
//   halfs h[9..17] : n0,n1,n2   (fp16)
//   bytes b[36..44]: c0,c1,c2   (unorm8, 1/255 scale)
//   bytes b[45..47]: pad
#define FD_OFFSET 82944   // align_up(3*6890*4, 256)

union FaceRec { uint4 q[3]; __half h[18]; unsigned char b[48]; };

__global__ __launch_bounds__(256)
void face_normals(const float* __restrict__ verts,
                  const int*   __restrict__ faces,
                  float* __restrict__ vnAcc) {
    int i = blockIdx.x * blockDim.x + threadIdx.x;
    if (i >= FC_) return;
    int f0 = faces[i*3+0], f1 = faces[i*3+1], f2 = faces[i*3+2];
    float p0x = verts[f0*3+0], p0y = verts[f0*3+1], p0z = verts[f0*3+2];
    float p1x = verts[f1*3+0], p1y = verts[f1*3+1], p1z = verts[f1*3+2];
    float p2x = verts[f2*3+0], p2y = verts[f2*3+1], p2z = verts[f2*3+2];
    float e1x = p1x-p0x, e1y = p1y-p0y, e1z = p1z-p0z;
    float e2x = p2x-p0x, e2y = p2y-p0y, e2z = p2z-p0z;
    float fnx = e1y*e2z - e1z*e2y;
    float fny = e1z*e2x - e1x*e2z;
    float fnz = e1x*e2y - e1y*e2x;
    atomicAdd(&vnAcc[f0*3+0], fnx); atomicAdd(&vnAcc[f0*3+1], fny); atomicAdd(&vnAcc[f0*3+2], fnz);
    atomicAdd(&vnAcc[f1*3+0], fnx); atomicAdd(&vnAcc[f1*3+1], fny); atomicAdd(&vnAcc[f1*3+2], fnz);
    atomicAdd(&vnAcc[f2*3+0], fnx); atomicAdd(&vnAcc[f2*3+1], fny); atomicAdd(&vnAcc[f2*3+2], fnz);
}

__global__ __launch_bounds__(256)
void vn_normalize(float* __restrict__ vn) {
    int i = blockIdx.x * blockDim.x + threadIdx.x;
    if (i >= V_) return;
    float x = vn[i*3+0], y = vn[i*3+1], z = vn[i*3+2];
    float inv = frsq(fmaxf(x*x + y*y + z*z, 1e-12f));
    vn[i*3+0] = x*inv; vn[i*3+1] = y*inv; vn[i*3+2] = z*inv;
}

__global__ __launch_bounds__(256)
void face_pack(const int*   __restrict__ faces,
               const float* __restrict__ verts,
               const float* __restrict__ vcol,
               const float* __restrict__ vn,
               uint4* __restrict__ fd) {
    int i = blockIdx.x * blockDim.x + threadIdx.x;
    if (i >= FC_) return;
    int f[3] = { faces[i*3+0], faces[i*3+1], faces[i*3+2] };
    FaceRec R;
    #pragma unroll
    for (int v = 0; v < 3; ++v) {
        R.h[v*3+0] = __float2half(verts[f[v]*3+0]);
        R.h[v*3+1] = __float2half(verts[f[v]*3+1]);
        R.h[v*3+2] = __float2half(verts[f[v]*3+2]);
        R.h[9+v*3+0] = __float2half(vn[f[v]*3+0]);
        R.h[9+v*3+1] = __float2half(vn[f[v]*3+1]);
        R.h[9+v*3+2] = __float2half(vn[f[v]*3+2]);
        R.b[36+v*3+0] = (unsigned char)lrintf(vcol[f[v]*3+0]*255.0f);
        R.b[36+v*3+1] = (unsigned char)lrintf(vcol[f[v]*3+1]*255.0f);
        R.b[36+v*3+2] = (unsigned char)lrintf(vcol[f[v]*3+2]*255.0f);
    }
    R.b[45] = R.b[46] = R.b[47] = 0;
    uint4* o = fd + (size_t)i * 3;
    o[0] = R.q[0]; o[1] = R.q[1]; o[2] = R.q[2];
}

// 32 lanes per pixel, 1 sample per lane (j<28 active).
__global__ __launch_bounds__(256)
void pixel_kernel(const int*   __restrict__ ptf,
                  const float* __restrict__ bary,
                  const float* __restrict__ dists,
                  const float* __restrict__ zbuf,
                  const uint4* __restrict__ fd,   // 3 uint4 per face
                  const float* __restrict__ light,
                  const float* __restrict__ amb,
                  const float* __restrict__ dif,
                  const float* __restrict__ spec,
                  const float* __restrict__ cam,
                  float* __restrict__ out) {
    int tid = blockIdx.x * blockDim.x + threadIdx.x;
    int pix = tid >> 5;
    int j   = tid & 31;
    if (pix >= NPIX) return;

    bool act = (j < K_);
    size_t sbase = (size_t)pix * K_ + j;

    int pf = -1;
    float d = 0.0f, z = 0.0f, w0 = 0.0f, w1 = 0.0f, w2 = 0.0f;
    if (act) {
        pf = ptf[sbase];
        d  = dists[sbase];
        z  = zbuf[sbase];
        float2 b01 = *(const float2*)(bary + sbase*3);
        w0 = b01.x; w1 = b01.y;
        w2 = bary[sbase*3+2];
        out[(size_t)NPIX*4 + sbase] = z;   // zbuf passthrough
    }

    float zi = 0.0f, prob = 0.0f, cr = 0.0f, cg = 0.0f, cb = 0.0f;
    if (pf >= 0) {
        prob = frcp(1.0f + fexp(d * SIGMA_INV));   // sigmoid(-d/sigma)
        zi   = (ZFAR_ - z) * ZSCALE;               // in [0.89, 0.99] for z in [2,12]

        const uint4* g = fd + (size_t)pf * 3;
        FaceRec F;
        F.q[0] = g[0]; F.q[1] = g[1]; F.q[2] = g[2];

        float px = w0*__half2float(F.h[0]) + w1*__half2float(F.h[3]) + w2*__half2float(F.h[6]);
        float py = w0*__half2float(F.h[1]) + w1*__half2float(F.h[4]) + w2*__half2float(F.h[7]);
        float pz = w0*__half2float(F.h[2]) + w1*__half2float(F.h[5]) + w2*__half2float(F.h[8]);
        float nux = w0*__half2float(F.h[9])  + w1*__half2float(F.h[12]) + w2*__half2float(F.h[15]);
        float nuy = w0*__half2float(F.h[10]) + w1*__half2float(F.h[13]) + w2*__half2float(F.h[16]);
        float nuz = w0*__half2float(F.h[11]) + w1*__half2float(F.h[14]) + w2*__half2float(F.h[17]);
        const float s255 = 1.0f/255.0f;
        float tr = (w0*(float)F.b[36] + w1*(float)F.b[39] + w2*(float)F.b[42]) * s255;
        float tg = (w0*(float)F.b[37] + w1*(float)F.b[40] + w2*(float)F.b[43]) * s255;
        float tb = (w0*(float)F.b[38] + w1*(float)F.b[41] + w2*(float)F.b[44]) * s255;

        float ninv = frsq(fmaxf(nux*nux + nuy*nuy + nuz*nuz, 1e-12f));
        float nx = nux*ninv, ny = nuy*ninv, nz = nuz*ninv;

        float lvx = light[0] - px, lvy = light[1] - py, lvz = light[2] - pz;
        float linv = frsq(fmaxf(lvx*lvx + lvy*lvy + lvz*lvz, 1e-12f));
        lvx *= linv; lvy *= linv; lvz *= linv;
        float ldn = lvx*nx + lvy*ny + lvz*nz;
        float ndotl = fmaxf(ldn, 0.0f);

        float vvx = cam[0] - px, vvy = cam[1] - py, vvz = cam[2] - pz;
        float vinv = frsq(fmaxf(vvx*vvx + vvy*vvy + vvz*vvz, 1e-12f));
        vvx *= vinv; vvy *= vinv; vvz *= vinv;

        float rx = 2.0f*ldn*nx - lvx;
        float ry = 2.0f*ldn*ny - lvy;
        float rz = 2.0f*ldn*nz - lvz;
        float ca = fmaxf(rx*vvx + ry*vvy + rz*vvz, 0.0f);
        float p64 = ca*ca; p64 *= p64; p64 *= p64; p64 *= p64; p64 *= p64; p64 *= p64;

        cr = (amb[0] + dif[0]*ndotl)*tr + spec[0]*p64;
        cg = (amb[1] + dif[1]*ndotl)*tg + spec[1]*p64;
        cb = (amb[2] + dif[2]*ndotl)*tb + spec[2]*p64;
    }

    // zbuf sorted ascending -> z_inv descending -> max = first active lane's zi.
    unsigned long long mk = __ballot(pf >= 0);
    int wavelane  = threadIdx.x & 63;
    int groupbase = wavelane & 32;
    unsigned gm = (unsigned)(mk >> groupbase);
    float m = EPS_;
    int src = groupbase + (gm ? (int)__builtin_ctz(gm) : 0);
    float mshfl = __shfl(zi, src, 64);
    if (gm) m = mshfl;

    float w = prob * fexp((zi - m) * GAMMA_INV);   // underflows to 0 for inactive
    float swr = w * cr, swg = w * cg, swb = w * cb;
    float om  = 1.0f - prob;
    #pragma unroll
    for (int o = 16; o; o >>= 1) {
        w   += __shfl_xor(w,   o, 32);
        swr += __shfl_xor(swr, o, 32);
        swg += __shfl_xor(swg, o, 32);
        swb += __shfl_xor(swb, o, 32);
        om  *= __shfl_xor(om,  o, 32);
    }

    if (j == 0) {
        float deltaw = fexp((EPS_ - m) * GAMMA_INV);
        float inv = frcp(w + deltaw);
        float4 img;
        img.x = (swr + deltaw) * inv;   // BG = 1
        img.y = (swg + deltaw) * inv;
        img.z = (swb + deltaw) * inv;
        img.w = 1.0f - om;
        ((float4*)out)[pix] = img;
    }
}

extern "C" void kernel_launch(void* const* d_in, const int* in_sizes, int n_in,
                              void* d_out, int out_size, void* d_ws, size_t ws_size,
                              hipStream_t stream) {
    const float* verts = (const float*)d_in[0];
    const float* vcol  = (const float*)d_in[1];
    const int*   faces = (const int*)d_in[2];
    const int*   ptf   = (const int*)d_in[3];
    const float* bary  = (const float*)d_in[4];
    const float* dists = (const float*)d_in[5];
    const float* zbuf  = (const float*)d_in[6];
    const float* light = (const float*)d_in[7];
    const float* amb   = (const float*)d_in[8];
    const float* dif   = (const float*)d_in[9];
    const float* spec  = (const float*)d_in[10];
    const float* cam   = (const float*)d_in[11];
    float* out = (float*)d_out;

    float* vnAcc = (float*)d_ws;
    uint4* fdat  = (uint4*)((char*)d_ws + FD_OFFSET);

    hipMemsetAsync(vnAcc, 0, (size_t)V_ * 3 * sizeof(float), stream);
    face_normals<<<(FC_ + 255)/256, 256, 0, stream>>>(verts, faces, vnAcc);
    vn_normalize<<<(V_ + 255)/256, 256, 0, stream>>>(vnAcc);
    face_pack<<<(FC_ + 255)/256, 256, 0, stream>>>(faces, verts, vcol, vnAcc, fdat);

    int blocks = (NPIX * 32 + 255) / 256;
    pixel_kernel<<<blocks, 256, 0, stream>>>(
        ptf, bary, dists, zbuf, fdat,
        light, amb, dif, spec, cam, out);
}